// Round 8
// baseline (318.271 us; speedup 1.0000x reference)
//
#include <hip/hip_runtime.h>
#include <cmath>
#include <cstdint>

// Shapes (fixed for this problem)
#define BB 4
#define SS 2048
#define EE 1024
#define HH 16
#define DD 64
#define ROWS (BB*SS)          // 8192
#define QKV_N (3*EE)          // 3072
#define NQT 16                // S / 128 q-tiles

using bf16x8 = __attribute__((ext_vector_type(8))) __bf16;
using bf16x4 = __attribute__((ext_vector_type(4))) __bf16;
using f32x4  = __attribute__((ext_vector_type(4))) float;
typedef __attribute__((ext_vector_type(4))) short short4v;

// log2(e) / sqrt(64): folded into Q columns in the QKV GEMM epilogue
#define SCQ 0.18033688f

__device__ inline f32x4 mfma16(bf16x8 a, bf16x8 b, f32x4 c) {
    return __builtin_amdgcn_mfma_f32_16x16x32_bf16(a, b, c, 0, 0, 0);
}

// K=16 MFMA: B-operand layout (k=4*quad+j, n=lane&15) == C/D layout ->
// exp'd S registers feed PV directly, no cross-lane movement. (verified R4-R7)
__device__ inline f32x4 mfma16k16(bf16x4 a, bf16x4 b, f32x4 c) {
    return __builtin_amdgcn_mfma_f32_16x16x16bf16_1k(
        __builtin_bit_cast(short4v, a), __builtin_bit_cast(short4v, b), c, 0, 0, 0);
}

__device__ inline void load_lds16(const void* g, void* l) {
    __builtin_amdgcn_global_load_lds(
        (__attribute__((address_space(1))) void*)g,
        (__attribute__((address_space(3))) void*)l, 16, 0, 0);
}

// ---------------- fused preprocessing: cast x + transpose both weights ----------------
// blocks [0,8192): cast x -> bf16 (4 elem/thread)
// blocks [8192,11264): w_qkv [1024][3072] -> wqkvT [3072][1024]
// blocks [11264,12288): w_proj [1024][1024] -> wprojT [1024][1024]
#define PREP_CAST 8192
#define PREP_TQKV 3072
__global__ __launch_bounds__(256) void prep(const float* __restrict__ x,
                                            const float* __restrict__ w_qkv,
                                            const float* __restrict__ w_proj,
                                            __bf16* __restrict__ xb,
                                            __bf16* __restrict__ wqkvT,
                                            __bf16* __restrict__ wprojT) {
    __shared__ float tile[32][33];
    const int bid = blockIdx.x, tid = threadIdx.x;
    if (bid < PREP_CAST) {
        size_t i = ((size_t)bid * 256 + tid) * 4;
        float4 v = *(const float4*)(x + i);
        bf16x4 o;
        o[0] = (__bf16)v.x; o[1] = (__bf16)v.y; o[2] = (__bf16)v.z; o[3] = (__bf16)v.w;
        *(bf16x4*)(xb + i) = o;
        return;
    }
    const float* in;
    __bf16* out;
    int N, n0, k0;
    if (bid < PREP_CAST + PREP_TQKV) {
        int b2 = bid - PREP_CAST;
        in = w_qkv; out = wqkvT; N = QKV_N;
        n0 = (b2 % (QKV_N / 32)) * 32; k0 = (b2 / (QKV_N / 32)) * 32;
    } else {
        int b3 = bid - PREP_CAST - PREP_TQKV;
        in = w_proj; out = wprojT; N = EE;
        n0 = (b3 % (EE / 32)) * 32; k0 = (b3 / (EE / 32)) * 32;
    }
    const int tx = tid & 31, ty = tid >> 5;
#pragma unroll
    for (int i = 0; i < 4; ++i)
        tile[ty + 8 * i][tx] = in[(size_t)(k0 + ty + 8 * i) * N + n0 + tx];
    __syncthreads();
#pragma unroll
    for (int i = 0; i < 4; ++i)
        out[(size_t)(n0 + ty + 8 * i) * EE + k0 + tx] = (__bf16)tile[tx][ty + 8 * i];
}

// ---------------- V transpose: qkv V-section -> vt[b][h][d][s] bf16 ----------------
__global__ __launch_bounds__(256) void build_vt(const __bf16* __restrict__ qkv,
                                                __bf16* __restrict__ vt) {
    __shared__ __bf16 tile[64 * 72];   // [s][d] padded
    const int s0 = blockIdx.x * 64, h = blockIdx.y, b = blockIdx.z;
    const int tid = threadIdx.x;
#pragma unroll
    for (int r = 0; r < 2; ++r) {
        int c = r * 256 + tid;                 // 0..511
        int s = c >> 3, dp = c & 7;
        bf16x8 v = *(const bf16x8*)(qkv + (size_t)(b * SS + s0 + s) * QKV_N + 2048 + h * 64 + dp * 8);
        *(bf16x8*)(tile + s * 72 + dp * 8) = v;
    }
    __syncthreads();
#pragma unroll
    for (int r = 0; r < 2; ++r) {
        int c = r * 256 + tid;
        int d = c >> 3, sp = c & 7;
        bf16x8 o;
#pragma unroll
        for (int i = 0; i < 8; ++i) o[i] = tile[(sp * 8 + i) * 72 + d];
        *(bf16x8*)(vt + (size_t)((b * HH + h) * 64 + d) * SS + s0 + sp * 8) = o;
    }
}

// ---------------- GEMM: C[M][N] = A[M][K] @ Bt[N][K]^T + bias ----------------
// QSCALE: multiply columns [0,EE) by SCQ (folds attention scale into Q).
template <bool OUT_BF16, bool QSCALE>
__global__ __launch_bounds__(256) void gemm_bt(const __bf16* __restrict__ A,
                                               const __bf16* __restrict__ Bt,
                                               const float* __restrict__ bias,
                                               void* __restrict__ Cout,
                                               int M, int N, int K) {
    __shared__ __bf16 As[128 * 32];
    __shared__ __bf16 Bs[128 * 32];
    const int tid  = threadIdx.x;
    const int wave = tid >> 6;
    const int lane = tid & 63;
    const int lrow = lane & 15;
    const int quad = lane >> 4;
    const int wm   = (wave >> 1) * 64;
    const int wn   = (wave & 1) * 64;
    const int tm   = blockIdx.x * 128;
    const int tn   = blockIdx.y * 128;

    f32x4 acc[4][4] = {};

    const int srow = lane >> 2;
    const int skoff = (lane & 3) * 8;

    for (int k0 = 0; k0 < K; k0 += 32) {
        __syncthreads();
#pragma unroll
        for (int i = 0; i < 2; ++i) {
            int c = wave * 2 + i;
            int row = 16 * c + srow;
            load_lds16(A + (size_t)(tm + row) * K + k0 + skoff, As + c * 512);
            load_lds16(Bt + (size_t)(tn + row) * K + k0 + skoff, Bs + c * 512);
        }
        __syncthreads();

        bf16x8 bfr[4];
#pragma unroll
        for (int ni = 0; ni < 4; ++ni)
            bfr[ni] = *(const bf16x8*)(Bs + (wn + ni * 16 + lrow) * 32 + quad * 8);
#pragma unroll
        for (int mi = 0; mi < 4; ++mi) {
            bf16x8 a = *(const bf16x8*)(As + (wm + mi * 16 + lrow) * 32 + quad * 8);
#pragma unroll
            for (int ni = 0; ni < 4; ++ni)
                acc[mi][ni] = mfma16(a, bfr[ni], acc[mi][ni]);
        }
    }

#pragma unroll
    for (int ni = 0; ni < 4; ++ni) {
        int cn = tn + wn + ni * 16 + lrow;
        float bv = bias[cn];
        float sc = (QSCALE && cn < EE) ? SCQ : 1.0f;
#pragma unroll
        for (int mi = 0; mi < 4; ++mi) {
#pragma unroll
            for (int r = 0; r < 4; ++r) {
                int gm = tm + wm + mi * 16 + quad * 4 + r;
                float v = (acc[mi][ni][r] + bv) * sc;
                if (OUT_BF16)
                    ((__bf16*)Cout)[(size_t)gm * N + cn] = (__bf16)v;
                else
                    ((float*)Cout)[(size_t)gm * N + cn] = v;
            }
        }
    }
}

// ---------------- Flash attention v8 ----------------
// v7 grid/XCD mapping + VALU cuts: unchunked 128-key softmax (one reduction
// pass per group per iter), all swizzle/staging addressing hoisted out of the
// k-loop, diagonal handled by mask only (no compute-skip branches).
__global__ __launch_bounds__(256) void attn8(const __bf16* __restrict__ qkv,
                                             const __bf16* __restrict__ vt,
                                             __bf16* __restrict__ y) {
    const int hb = blockIdx.x;                 // fast dim: h + 16*b -> XCD = hb%8
    const int h = hb & 15, b = hb >> 4;
    const int j = blockIdx.y;                  // 0..NQT/2-1
    const int tid = threadIdx.x;
    const int wave = tid >> 6, lane = tid & 63;
    const int lrow = lane & 15, quad = lane >> 4;

    __shared__ __bf16 Klds[2][128 * 64];   // [key][d-chunk8 ^ (key&7)]          2x16 KB
    __shared__ __bf16 Vlds[2][64 * 128];   // [d][k-chunk8: bit3 thru, ^ (d&7)]  2x16 KB

    const __bf16* kbase = qkv + (size_t)b * SS * QKV_N + 1024 + h * 64;
    const __bf16* vbase = vt + (size_t)(b * HH + h) * 64 * SS;

    // ---- loop-invariant addressing (hoisted out of the k-loop) ----
    const __bf16* kptr[4];    // staging: global base per chunk-row
    const __bf16* vptr[4];
#pragma unroll
    for (int r = 0; r < 4; ++r) {
        int c = r * 256 + tid;
        int row = c >> 3;
        int g8 = ((c & 7) ^ (row & 7)) * 8;
        kptr[r] = kbase + (size_t)row * QKV_N + g8;
        int d = c >> 4, kc = c & 15;
        int vg8 = ((kc & 8) | ((kc & 7) ^ (d & 7))) * 8;
        vptr[r] = vbase + (size_t)d * SS + vg8;
    }
    const int koff0 = lrow * 64 + 8 * (quad ^ (lrow & 7));        // K-frag reads
    const int koff1 = lrow * 64 + 8 * ((4 + quad) ^ (lrow & 7));
    int voff[8];                                                   // PV V-frag reads
#pragma unroll
    for (int tt = 0; tt < 8; ++tt) {
        int klog = 2 * tt + (quad >> 1);
        int c = (klog & 8) | ((klog & 7) ^ (lrow & 7));
        voff[tt] = lrow * 128 + c * 8 + 4 * (quad & 1);
    }

    auto stage = [&](int kb2, __bf16* Kb, __bf16* Vb) {
#pragma unroll
        for (int r = 0; r < 4; ++r) {
            load_lds16(kptr[r] + (size_t)kb2 * QKV_N, Kb + (r * 256 + tid) * 8);
            load_lds16(vptr[r] + kb2, Vb + (r * 256 + tid) * 8);
        }
    };

    const int qtA = NQT - 1 - j, qtB = j;
    const int nA = qtA + 1, total = nA + qtB + 1;

    stage(0, Klds[0], Vlds[0]);   // prime buffer 0

    int it = 0;
    for (int seg = 0; seg < 2; ++seg) {
        const int qtile = seg ? qtB : qtA;
        const int qbase = qtile * 128;

        // Q fragments (B-operand): q col = lrow; group g -> rows qbase+64g+16w+lrow
        bf16x8 qf[2][2];
#pragma unroll
        for (int g = 0; g < 2; ++g) {
            const __bf16* qp = qkv + (size_t)(b * SS + qbase + 64 * g + wave * 16 + lrow) * QKV_N + h * 64;
            qf[g][0] = *(const bf16x8*)(qp + quad * 8);
            qf[g][1] = *(const bf16x8*)(qp + 32 + quad * 8);
        }
        const int q0 = qbase + wave * 16 + lrow;

        float m[2] = {-INFINITY, -INFINITY}, l[2] = {0.f, 0.f};
        f32x4 oacc[2][4] = {};   // O^T: d = 16*td + 4*quad + r, q col = lrow

        for (int kb_i = 0; kb_i <= qtile; ++kb_i, ++it) {
            const int cur = it & 1;
            const int kb = kb_i * 128;
            const bool diag = (kb_i == qtile);
            __syncthreads();   // buf[cur] staged; all waves done with buf[cur^1]
            if (it + 1 < total) {
                int nit = it + 1;
                int nkb = (nit < nA ? nit : nit - nA) * 128;
                stage(nkb, Klds[cur ^ 1], Vlds[cur ^ 1]);
            }
            const __bf16* Kb = Klds[cur];
            const __bf16* Vb = Vlds[cur];

            // QK^T: all 8 key tiles of 16, both q-groups (K frags shared)
            f32x4 s0[8], s1[8];
#pragma unroll
            for (int tt = 0; tt < 8; ++tt) {
                bf16x8 kf0 = *(const bf16x8*)(Kb + tt * 1024 + koff0);
                bf16x8 kf1 = *(const bf16x8*)(Kb + tt * 1024 + koff1);
                f32x4 c0 = {};
                c0 = mfma16(kf0, qf[0][0], c0);
                c0 = mfma16(kf1, qf[0][1], c0);
                s0[tt] = c0;
                f32x4 c1 = {};
                c1 = mfma16(kf0, qf[1][0], c1);
                c1 = mfma16(kf1, qf[1][1], c1);
                s1[tt] = c1;
            }

            if (diag) {   // mask only; exp(-inf)=0 makes PV contributions vanish
#pragma unroll
                for (int tt = 0; tt < 8; ++tt)
#pragma unroll
                    for (int r = 0; r < 4; ++r) {
                        int key = kb + 16 * tt + 4 * quad + r;
                        if (key > q0)      s0[tt][r] = -INFINITY;
                        if (key > q0 + 64) s1[tt][r] = -INFINITY;
                    }
            }

            // online softmax: ONE reduction pass per group over all 128 keys
            bf16x4 p0[8], p1[8];
#pragma unroll
            for (int g = 0; g < 2; ++g) {
                f32x4* s = g ? s1 : s0;
                bf16x4* p = g ? p1 : p0;
                float mx = -INFINITY;
#pragma unroll
                for (int tt = 0; tt < 8; ++tt)
                    mx = fmaxf(mx, fmaxf(fmaxf(s[tt][0], s[tt][1]), fmaxf(s[tt][2], s[tt][3])));
                mx = fmaxf(mx, __shfl_xor(mx, 16));
                mx = fmaxf(mx, __shfl_xor(mx, 32));
                float mnew = fmaxf(m[g], mx);
                float alpha = exp2f(m[g] - mnew);
                m[g] = mnew;
                float rs = 0.f;
#pragma unroll
                for (int tt = 0; tt < 8; ++tt) {
                    bf16x4 pk;
#pragma unroll
                    for (int r = 0; r < 4; ++r) {
                        float e = exp2f(s[tt][r] - mnew);
                        rs += e;
                        pk[r] = (__bf16)e;
                    }
                    p[tt] = pk;
                }
                rs += __shfl_xor(rs, 16);
                rs += __shfl_xor(rs, 32);
                l[g] = l[g] * alpha + rs;
#pragma unroll
                for (int td = 0; td < 4; ++td) {
                    oacc[g][td][0] *= alpha; oacc[g][td][1] *= alpha;
                    oacc[g][td][2] *= alpha; oacc[g][td][3] *= alpha;
                }
            }

            // PV: O^T += V^T P^T, K=16 per key tile; V frags shared across groups
#pragma unroll
            for (int tt = 0; tt < 8; ++tt) {
                const __bf16* vc = Vb + voff[tt];
#pragma unroll
                for (int td = 0; td < 4; ++td) {
                    bf16x4 vf = *(const bf16x4*)(vc + td * 2048);
                    oacc[0][td] = mfma16k16(vf, p0[tt], oacc[0][td]);
                    oacc[1][td] = mfma16k16(vf, p1[tt], oacc[1][td]);
                }
            }
        }

        // epilogue: y[q][h*64 + 16*td + 4*quad + r], packed 8B stores
#pragma unroll
        for (int g = 0; g < 2; ++g) {
            float linv = 1.f / l[g];
            __bf16* yp = y + (size_t)(b * SS + qbase + 64 * g + wave * 16 + lrow) * EE + h * 64;
#pragma unroll
            for (int td = 0; td < 4; ++td) {
                bf16x4 o;
#pragma unroll
                for (int r = 0; r < 4; ++r) o[r] = (__bf16)(oacc[g][td][r] * linv);
                *(bf16x4*)(yp + 16 * td + 4 * quad) = o;
            }
        }
    }
}

// ---------------- launch ----------------
extern "C" void kernel_launch(void* const* d_in, const int* in_sizes, int n_in,
                              void* d_out, int out_size, void* d_ws, size_t ws_size,
                              hipStream_t stream) {
    const float* x      = (const float*)d_in[0];
    const float* w_qkv  = (const float*)d_in[1];
    const float* b_qkv  = (const float*)d_in[2];
    const float* w_proj = (const float*)d_in[3];
    const float* b_proj = (const float*)d_in[4];
    float* out = (float*)d_out;

    __bf16* xb     = (__bf16*)d_ws;                      // 16 MB (reused as vt later)
    __bf16* wqkvT  = xb + (size_t)ROWS * EE;             // [3072][1024]
    __bf16* wprojT = wqkvT + (size_t)QKV_N * EE;         // [1024][1024]
    __bf16* qkv    = wprojT + (size_t)EE * EE;           // [8192][3072]
    __bf16* yb     = qkv + (size_t)ROWS * QKV_N;         // [8192][1024]
    __bf16* vtb    = xb;                                 // alias: xb dead after GEMM1

    prep<<<dim3(PREP_CAST + PREP_TQKV + EE * EE / 1024), dim3(256), 0, stream>>>(
        x, w_qkv, w_proj, xb, wqkvT, wprojT);
    gemm_bt<true, true><<<dim3(ROWS / 128, QKV_N / 128), dim3(256), 0, stream>>>(
        xb, wqkvT, b_qkv, (void*)qkv, ROWS, QKV_N, EE);
    build_vt<<<dim3(SS / 64, HH, BB), dim3(256), 0, stream>>>(qkv, vtb);
    attn8<<<dim3(HH * BB, NQT / 2), dim3(256), 0, stream>>>(qkv, vtb, yb);
    gemm_bt<false, false><<<dim3(ROWS / 128, EE / 128), dim3(256), 0, stream>>>(
        yb, wprojT, b_proj, (void*)out, ROWS, EE, EE);
}